// Round 11
// baseline (427.459 us; speedup 1.0000x reference)
//
#include <hip/hip_runtime.h>

#define BATCH 64
#define N_IN  2048
#define NN    512
#define G     4
#define ALPHA 0.995f
#define BETA  0.975f
#define V_TH  2.0f

// ---------- fused finisher: runs in the LAST block of a bq-group ----------
// 1024 threads, batches b0..b0+G-1. Uses smem[0..24KB).
__device__ __forceinline__ void finish_bq(
    int b0, int KRV,
    const float* __restrict__ v, const float* __restrict__ z,
    const float* __restrict__ z_out, const float* __restrict__ w,
    const float* __restrict__ ws, float* __restrict__ out,
    char* smem)
{
    const int tid = threadIdx.x;
    float (*zlds)[NN]    = (float (*)[NN])smem;             // 8 KB
    float (*r2)[G][NN]   = (float (*)[G][NN])(smem + 8192); // 16 KB

    for (int i = tid; i < G * NN; i += 1024) {
        const int g = i >> 9, idx = i & 511;
        zlds[g][idx] = BETA * z_out[(b0 + g) * NN + idx] + z[(b0 + g) * NN + idx];
    }
    __syncthreads();

    // drive2: thread owns n; w2 row element loaded once, reused across G batches
    const int n  = tid & 511;
    const int jh = tid >> 9;             // j parity
    float d2g[G] = {0.f, 0.f, 0.f, 0.f};
    for (int j = jh; j < NN - 1; j += 2) {
        const float wv = w[(size_t)(N_IN + j) * NN + n];   // coalesced, L2-hot
        const int jz = j + (j >= n);                       // LDS broadcast
#pragma unroll
        for (int g = 0; g < G; ++g) d2g[g] += zlds[g][jz] * wv;
    }
#pragma unroll
    for (int g = 0; g < G; ++g) r2[jh][g][n] = d2g[g];
    __syncthreads();

    if (tid < NN) {
#pragma unroll
        for (int g = 0; g < G; ++g) {
            float d1 = 0.f;
            for (int kr = 0; kr < KRV; ++kr)
                d1 += ws[((size_t)kr * BATCH + b0 + g) * NN + tid];
            const float d2 = r2[0][g][tid] + r2[1][g][tid];
            const float vv = v[(b0 + g) * NN + tid];
            const float zz = z[(b0 + g) * NN + tid];
            const float v_new = ALPHA * vv + d1 + d2 - V_TH * zz;
            out[(b0 + g) * NN + tid]                  = v_new;
            out[BATCH * NN + (b0 + g) * NN + tid]     = (v_new - V_TH > 0.f) ? 1.f : 0.f;
            out[2 * BATCH * NN + (b0 + g) * NN + tid] = zlds[g][tid];
        }
    }
}

// ---------- fused A: KR=32, full-row contiguous streaming (needs 4MB+64 ws) ----------
__global__ __launch_bounds__(1024, 8)
void fused32(const float* __restrict__ x, const float* __restrict__ w,
             const float* __restrict__ v, const float* __restrict__ z,
             const float* __restrict__ z_out,
             float* __restrict__ ws, int* __restrict__ cnt,
             float* __restrict__ out)
{
    __shared__ __align__(16) char smem[65536];
    const int kr  = blockIdx.x;          // 0..31
    const int bq  = blockIdx.y;          // 0..15
    const int b0  = bq * G;
    const int tid = threadIdx.x;
    const int c4  = tid & 127;
    const int kl  = tid >> 7;

    const float4* __restrict__ x4 = (const float4*)x;
    const float4* __restrict__ w4 = (const float4*)w;
    const int k0 = kr * 64 + kl;

    size_t xoff[G];
#pragma unroll
    for (int g = 0; g < G; ++g)
        xoff[g] = ((size_t)(b0 + g) * N_IN + k0) * 128 + c4;
    size_t woff = (size_t)k0 * 128 + c4;
    const size_t kstep = 8 * 128;

    float4 acc[G];
#pragma unroll
    for (int g = 0; g < G; ++g) acc[g] = make_float4(0.f, 0.f, 0.f, 0.f);

#pragma unroll 2
    for (int i = 0; i < 8; ++i) {
        float4 xv[G];
#pragma unroll
        for (int g = 0; g < G; ++g) xv[g] = x4[xoff[g]];
        const float4 wv = w4[woff];
#pragma unroll
        for (int g = 0; g < G; ++g) {
            acc[g].x += xv[g].x * wv.x;
            acc[g].y += xv[g].y * wv.y;
            acc[g].z += xv[g].z * wv.z;
            acc[g].w += xv[g].w * wv.w;
        }
#pragma unroll
        for (int g = 0; g < G; ++g) xoff[g] += kstep;
        woff += kstep;
    }

    float4 (*red)[8][128] = (float4 (*)[8][128])smem;   // 64 KB
#pragma unroll
    for (int g = 0; g < G; ++g) red[g][kl][c4] = acc[g];
    __syncthreads();

    if (tid < 512) {
        const int g = tid >> 7, c = tid & 127;
        float4 s = red[g][0][c];
#pragma unroll
        for (int l = 1; l < 8; ++l) {
            const float4 o = red[g][l][c];
            s.x += o.x; s.y += o.y; s.z += o.z; s.w += o.w;
        }
        ((float4*)ws)[((size_t)kr * BATCH + b0 + g) * 128 + c] = s;
    }
    __threadfence();                      // release our ws stores (device scope)
    __syncthreads();

    __shared__ int ticket;
    if (tid == 0) ticket = atomicAdd(&cnt[bq], 1);
    __syncthreads();
    if (ticket != 31) return;             // not last: done
    __threadfence();                      // acquire: see all 32 blocks' ws

    finish_bq(b0, 32, v, z, z_out, w, ws, out, smem);
}

// ---------- fused B: KR=4, nc-split geometry (needs 1MB+64 ws) ----------
__global__ __launch_bounds__(1024, 8)
void fused4(const float* __restrict__ x, const float* __restrict__ w,
            const float* __restrict__ v, const float* __restrict__ z,
            const float* __restrict__ z_out,
            float* __restrict__ ws, int* __restrict__ cnt,
            float* __restrict__ out)
{
    __shared__ __align__(16) char smem[24576];
    const int nc   = blockIdx.x;         // 0..7
    const int bq   = blockIdx.y;         // 0..15
    const int kr   = blockIdx.z;         // 0..3
    const int b0   = bq * G;
    const int tid  = threadIdx.x;
    const int nl   = tid & 15;
    const int kk   = tid >> 4;
    const int wid  = tid >> 6;
    const int lane = tid & 63;

    const float4* __restrict__ x4 = (const float4*)x;
    const float4* __restrict__ w4 = (const float4*)w;
    const int c4    = nc * 16 + nl;
    const int kbase = kr * 512 + kk;

    size_t xoff[G];
#pragma unroll
    for (int g = 0; g < G; ++g)
        xoff[g] = ((size_t)(b0 + g) * N_IN + kbase) * 128 + c4;
    size_t woff = (size_t)kbase * 128 + c4;
    const size_t kstep = (size_t)64 * 128;

    float4 acc[G];
#pragma unroll
    for (int g = 0; g < G; ++g) acc[g] = make_float4(0.f, 0.f, 0.f, 0.f);

#pragma unroll 2
    for (int i = 0; i < 8; ++i) {
        float4 xv[G];
#pragma unroll
        for (int g = 0; g < G; ++g) xv[g] = x4[xoff[g]];
        const float4 wv = w4[woff];
#pragma unroll
        for (int g = 0; g < G; ++g) {
            acc[g].x += xv[g].x * wv.x;
            acc[g].y += xv[g].y * wv.y;
            acc[g].z += xv[g].z * wv.z;
            acc[g].w += xv[g].w * wv.w;
        }
#pragma unroll
        for (int g = 0; g < G; ++g) xoff[g] += kstep;
        woff += kstep;
    }

#pragma unroll
    for (int off = 32; off >= 16; off >>= 1) {
#pragma unroll
        for (int g = 0; g < G; ++g) {
            acc[g].x += __shfl_down(acc[g].x, off);
            acc[g].y += __shfl_down(acc[g].y, off);
            acc[g].z += __shfl_down(acc[g].z, off);
            acc[g].w += __shfl_down(acc[g].w, off);
        }
    }

    float4 (*wpart)[G][16] = (float4 (*)[G][16])smem;   // 16 KB
    if (lane < 16) {
#pragma unroll
        for (int g = 0; g < G; ++g) wpart[wid][g][lane] = acc[g];
    }
    __syncthreads();

    if (tid < 64) {
        const int g = tid >> 4, c = tid & 15;
        float4 s = wpart[0][g][c];
#pragma unroll
        for (int ww = 1; ww < 16; ++ww) {
            const float4 o = wpart[ww][g][c];
            s.x += o.x; s.y += o.y; s.z += o.z; s.w += o.w;
        }
        ((float4*)ws)[((size_t)kr * BATCH + b0 + g) * 128 + nc * 16 + c] = s;
    }
    __threadfence();
    __syncthreads();

    __shared__ int ticket;
    if (tid == 0) ticket = atomicAdd(&cnt[bq], 1);
    __syncthreads();
    if (ticket != 31) return;            // 8 nc x 4 kr = 32 blocks per bq
    __threadfence();

    finish_bq(b0, 4, v, z, z_out, w, ws, out, smem);
}

// ---------- fallback: R10 two-kernel path (exactly 1MB ws) ----------
__global__ __launch_bounds__(1024, 8)
void k1_fallback(const float* __restrict__ x, const float* __restrict__ w,
                 float4* __restrict__ ws)
{
    const int nc  = blockIdx.x;
    const int b0  = blockIdx.y * G;
    const int kr  = blockIdx.z;
    const int tid = threadIdx.x;
    const int nl  = tid & 15;
    const int kk  = tid >> 4;
    const int wid  = tid >> 6;
    const int lane = tid & 63;

    const float4* __restrict__ x4 = (const float4*)x;
    const float4* __restrict__ w4 = (const float4*)w;
    const int c4    = nc * 16 + nl;
    const int kbase = kr * 512 + kk;

    size_t xoff[G];
#pragma unroll
    for (int g = 0; g < G; ++g)
        xoff[g] = ((size_t)(b0 + g) * N_IN + kbase) * 128 + c4;
    size_t woff = (size_t)kbase * 128 + c4;

    float4 acc[G];
#pragma unroll
    for (int g = 0; g < G; ++g) acc[g] = make_float4(0.f, 0.f, 0.f, 0.f);

    const size_t kstep = (size_t)64 * 128;
#pragma unroll 2
    for (int i = 0; i < 8; ++i) {
        float4 xv[G];
#pragma unroll
        for (int g = 0; g < G; ++g) xv[g] = x4[xoff[g]];
        const float4 wv = w4[woff];
#pragma unroll
        for (int g = 0; g < G; ++g) {
            acc[g].x += xv[g].x * wv.x;
            acc[g].y += xv[g].y * wv.y;
            acc[g].z += xv[g].z * wv.z;
            acc[g].w += xv[g].w * wv.w;
        }
#pragma unroll
        for (int g = 0; g < G; ++g) xoff[g] += kstep;
        woff += kstep;
    }

#pragma unroll
    for (int off = 32; off >= 16; off >>= 1) {
#pragma unroll
        for (int g = 0; g < G; ++g) {
            acc[g].x += __shfl_down(acc[g].x, off);
            acc[g].y += __shfl_down(acc[g].y, off);
            acc[g].z += __shfl_down(acc[g].z, off);
            acc[g].w += __shfl_down(acc[g].w, off);
        }
    }

    __shared__ float4 wpart[16][G][16];
    if (lane < 16) {
#pragma unroll
        for (int g = 0; g < G; ++g) wpart[wid][g][lane] = acc[g];
    }
    __syncthreads();

    if (tid < 64) {
        const int g = tid >> 4, c = tid & 15;
        float4 s = wpart[0][g][c];
#pragma unroll
        for (int ww = 1; ww < 16; ++ww) {
            const float4 o = wpart[ww][g][c];
            s.x += o.x; s.y += o.y; s.z += o.z; s.w += o.w;
        }
        ws[((size_t)kr * BATCH + b0 + g) * 128 + nc * 16 + c] = s;
    }
}

__global__ __launch_bounds__(1024)
void k2_finish(const float* __restrict__ v, const float* __restrict__ z,
               const float* __restrict__ z_out, const float* __restrict__ w,
               const float* __restrict__ ws, float* __restrict__ out)
{
    const int nc  = blockIdx.x;
    const int b   = blockIdx.y;
    const int nb  = nc * 64;
    const int tid = threadIdx.x;

    __shared__ float zlds[NN];
    __shared__ float r2[1024];

    if (tid < NN)
        zlds[tid] = BETA * z_out[b * NN + tid] + z[b * NN + tid];
    __syncthreads();

    const int n_loc = tid & 63;
    const int n     = nb + n_loc;
    const int jg    = tid >> 6;
    float d2 = 0.f;
#pragma unroll 4
    for (int j = jg; j < NN - 1; j += 16)
        d2 += zlds[j + (j >= n)] * w[(size_t)(N_IN + j) * NN + n];
    r2[tid] = d2;
    __syncthreads();

    if (tid < 64) {
        float d1 = 0.f;
#pragma unroll
        for (int kr = 0; kr < 4; ++kr)
            d1 += ws[((size_t)kr * BATCH + b) * NN + n];
        float d2s = 0.f;
#pragma unroll
        for (int g = 0; g < 16; ++g) d2s += r2[g * 64 + n_loc];
        const float vv    = v[b * NN + n];
        const float zz    = z[b * NN + n];
        const float v_new = ALPHA * vv + d1 + d2s - V_TH * zz;
        out[b * NN + n]                  = v_new;
        out[BATCH * NN + b * NN + n]     = (v_new - V_TH > 0.f) ? 1.f : 0.f;
        out[2 * BATCH * NN + b * NN + n] = zlds[n];
    }
}

extern "C" void kernel_launch(void* const* d_in, const int* in_sizes, int n_in,
                              void* d_out, int out_size, void* d_ws, size_t ws_size,
                              hipStream_t stream) {
    (void)in_sizes; (void)n_in; (void)out_size;
    const float* x     = (const float*)d_in[0];
    const float* v     = (const float*)d_in[1];
    const float* z     = (const float*)d_in[2];
    const float* z_out = (const float*)d_in[3];
    const float* w     = (const float*)d_in[4];
    float* out = (float*)d_out;
    float* wsf = (float*)d_ws;

    const size_t part32 = (size_t)32 * BATCH * NN * sizeof(float);  // 4 MB
    const size_t part4  = (size_t)4  * BATCH * NN * sizeof(float);  // 1 MB

    if (ws_size >= part32 + 64) {
        int* cnt = (int*)((char*)d_ws + part32);
        hipMemsetAsync(cnt, 0, 16 * sizeof(int), stream);
        dim3 g1(32, BATCH / G);
        fused32<<<g1, 1024, 0, stream>>>(x, w, v, z, z_out, wsf, cnt, out);
    } else if (ws_size >= part4 + 64) {
        int* cnt = (int*)((char*)d_ws + part4);
        hipMemsetAsync(cnt, 0, 16 * sizeof(int), stream);
        dim3 g1(8, BATCH / G, 4);
        fused4<<<g1, 1024, 0, stream>>>(x, w, v, z, z_out, wsf, cnt, out);
    } else {
        dim3 g1(8, BATCH / G, 4);
        k1_fallback<<<g1, 1024, 0, stream>>>(x, w, (float4*)wsf);
        dim3 g2(8, BATCH);
        k2_finish<<<g2, 1024, 0, stream>>>(v, z, z_out, w, wsf, out);
    }
}

// Round 12
// 49.732 us; speedup vs baseline: 8.5952x; 8.5952x over previous
//
#include <hip/hip_runtime.h>

#define BATCH 64
#define N_IN  2048
#define NN    512
#define G     4
#define ALPHA 0.995f
#define BETA  0.975f
#define V_TH  2.0f

// ---------------- K1: x-stream (R10-proven) + fold-in of drive2 j-slice ----------
// grid (kr 0..31, bq 0..15) = 512 blocks x 1024 thr, 2/CU, 32 waves/CU.
// Block (kr,bq): d1 partial over k-rows [64kr,64kr+64) AND d2 partial over
// j in [16kr, 16kr+16) for batches b0..b0+3. Both summed into ws[kr][b][n].
__global__ __launch_bounds__(1024, 8)
void k1_stream(const float* __restrict__ x, const float* __restrict__ w,
               const float* __restrict__ z, const float* __restrict__ z_out,
               float4* __restrict__ ws)
{
    __shared__ __align__(16) float4 red[G][8][128];   // 64 KB, reused below
    const int kr  = blockIdx.x;          // 0..31
    const int b0  = blockIdx.y * G;
    const int tid = threadIdx.x;
    const int c4  = tid & 127;
    const int kl  = tid >> 7;

    const float4* __restrict__ x4 = (const float4*)x;
    const float4* __restrict__ w4 = (const float4*)w;
    const int k0 = kr * 64 + kl;

    size_t xoff[G];
#pragma unroll
    for (int g = 0; g < G; ++g)
        xoff[g] = ((size_t)(b0 + g) * N_IN + k0) * 128 + c4;
    size_t woff = (size_t)k0 * 128 + c4;
    const size_t kstep = 8 * 128;

    float4 acc[G];
#pragma unroll
    for (int g = 0; g < G; ++g) acc[g] = make_float4(0.f, 0.f, 0.f, 0.f);

#pragma unroll 2
    for (int i = 0; i < 8; ++i) {        // 64 k-rows
        float4 xv[G];
#pragma unroll
        for (int g = 0; g < G; ++g) xv[g] = x4[xoff[g]];   // HBM streams first
        const float4 wv = w4[woff];                        // L2-hot second
#pragma unroll
        for (int g = 0; g < G; ++g) {
            acc[g].x += xv[g].x * wv.x;
            acc[g].y += xv[g].y * wv.y;
            acc[g].z += xv[g].z * wv.z;
            acc[g].w += xv[g].w * wv.w;
        }
#pragma unroll
        for (int g = 0; g < G; ++g) xoff[g] += kstep;
        woff += kstep;
    }

#pragma unroll
    for (int g = 0; g < G; ++g) red[g][kl][c4] = acc[g];
    __syncthreads();

    // d1 column sums -> registers (threads 0..511 own (g, c4))
    float4 s = make_float4(0.f, 0.f, 0.f, 0.f);
    if (tid < 512) {
        const int g = tid >> 7, c = tid & 127;
        s = red[g][0][c];
#pragma unroll
        for (int l = 1; l < 8; ++l) {
            const float4 o = red[g][l][c];
            s.x += o.x; s.y += o.y; s.z += o.z; s.w += o.w;
        }
    }
    __syncthreads();                     // red free for reuse now

    // ---- drive2 j-slice [j0, j0+16) for this block's 4 batches
    float* d2l = (float*)red;            // [G][512] floats, 8 KB
    float* zr  = d2l + G * NN;           // [G][17] z_out_new slice
    const int j0 = kr * 16;

    if (tid < G * 17) {                  // build z_out_new slice
        const int g = tid / 17, jj = tid % 17;
        const int idx = j0 + jj;
        if (idx < NN)
            zr[g * 17 + jj] = BETA * z_out[(b0 + g) * NN + idx]
                            + z[(b0 + g) * NN + idx];
    }
    __syncthreads();

    {
        const int n  = tid & 511;
        const int gh = tid >> 9;         // 0/1 -> batches {0,1} / {2,3}
        float p0 = 0.f, p1 = 0.f;
        const int jend = (j0 + 16 < NN - 1) ? j0 + 16 : NN - 1;
        for (int j = j0; j < jend; ++j) {
            const float wv = w[(size_t)(N_IN + j) * NN + n];  // coalesced, L2-hot
            const int jj = j + (j >= n) - j0;                 // LOO index in slice
            p0 += zr[(gh * 2 + 0) * 17 + jj] * wv;
            p1 += zr[(gh * 2 + 1) * 17 + jj] * wv;
        }
        d2l[(gh * 2 + 0) * NN + n] = p0;
        d2l[(gh * 2 + 1) * NN + n] = p1;
    }
    __syncthreads();

    if (tid < 512) {                     // combine d1 + d2 partials, store
        const int g = tid >> 7, c = tid & 127;
        s.x += d2l[g * NN + 4 * c + 0];
        s.y += d2l[g * NN + 4 * c + 1];
        s.z += d2l[g * NN + 4 * c + 2];
        s.w += d2l[g * NN + 4 * c + 3];
        ws[((size_t)kr * BATCH + b0 + g) * 128 + c] = s;
    }
}

// ---------------- K3: pure epilogue (sum 32 partials + pointwise) ----------------
__global__ __launch_bounds__(128)
void k3_epi(const float* __restrict__ v, const float* __restrict__ z,
            const float* __restrict__ z_out, const float* __restrict__ ws,
            float* __restrict__ out)
{
    const int i = blockIdx.x * 128 + threadIdx.x;   // 0 .. 64*512-1
    float d = 0.f;
#pragma unroll
    for (int kr = 0; kr < 32; ++kr)
        d += ws[(size_t)kr * (BATCH * NN) + i];     // coalesced, L2-hot
    const float zz = z[i];
    const float vn = ALPHA * v[i] + d - V_TH * zz;
    out[i]                  = vn;
    out[BATCH * NN + i]     = (vn - V_TH > 0.f) ? 1.f : 0.f;
    out[2 * BATCH * NN + i] = BETA * z_out[i] + zz;
}

// ---------------- fallback (ws < 4 MB): R10's proven two-kernel path ----------------
__global__ __launch_bounds__(1024, 8)
void k1_fallback(const float* __restrict__ x, const float* __restrict__ w,
                 float4* __restrict__ ws)
{
    const int nc  = blockIdx.x;
    const int b0  = blockIdx.y * G;
    const int kr  = blockIdx.z;
    const int tid = threadIdx.x;
    const int nl  = tid & 15;
    const int kk  = tid >> 4;
    const int wid  = tid >> 6;
    const int lane = tid & 63;

    const float4* __restrict__ x4 = (const float4*)x;
    const float4* __restrict__ w4 = (const float4*)w;
    const int c4    = nc * 16 + nl;
    const int kbase = kr * 512 + kk;

    size_t xoff[G];
#pragma unroll
    for (int g = 0; g < G; ++g)
        xoff[g] = ((size_t)(b0 + g) * N_IN + kbase) * 128 + c4;
    size_t woff = (size_t)kbase * 128 + c4;
    const size_t kstep = (size_t)64 * 128;

    float4 acc[G];
#pragma unroll
    for (int g = 0; g < G; ++g) acc[g] = make_float4(0.f, 0.f, 0.f, 0.f);

#pragma unroll 2
    for (int i = 0; i < 8; ++i) {
        float4 xv[G];
#pragma unroll
        for (int g = 0; g < G; ++g) xv[g] = x4[xoff[g]];
        const float4 wv = w4[woff];
#pragma unroll
        for (int g = 0; g < G; ++g) {
            acc[g].x += xv[g].x * wv.x;
            acc[g].y += xv[g].y * wv.y;
            acc[g].z += xv[g].z * wv.z;
            acc[g].w += xv[g].w * wv.w;
        }
#pragma unroll
        for (int g = 0; g < G; ++g) xoff[g] += kstep;
        woff += kstep;
    }

#pragma unroll
    for (int off = 32; off >= 16; off >>= 1) {
#pragma unroll
        for (int g = 0; g < G; ++g) {
            acc[g].x += __shfl_down(acc[g].x, off);
            acc[g].y += __shfl_down(acc[g].y, off);
            acc[g].z += __shfl_down(acc[g].z, off);
            acc[g].w += __shfl_down(acc[g].w, off);
        }
    }

    __shared__ float4 wpart[16][G][16];
    if (lane < 16) {
#pragma unroll
        for (int g = 0; g < G; ++g) wpart[wid][g][lane] = acc[g];
    }
    __syncthreads();

    if (tid < 64) {
        const int g = tid >> 4, c = tid & 15;
        float4 sf = wpart[0][g][c];
#pragma unroll
        for (int ww = 1; ww < 16; ++ww) {
            const float4 o = wpart[ww][g][c];
            sf.x += o.x; sf.y += o.y; sf.z += o.z; sf.w += o.w;
        }
        ws[((size_t)kr * BATCH + b0 + g) * 128 + nc * 16 + c] = sf;
    }
}

__global__ __launch_bounds__(1024)
void k2_finish(const float* __restrict__ v, const float* __restrict__ z,
               const float* __restrict__ z_out, const float* __restrict__ w,
               const float* __restrict__ ws, float* __restrict__ out)
{
    const int nc  = blockIdx.x;
    const int b   = blockIdx.y;
    const int nb  = nc * 64;
    const int tid = threadIdx.x;

    __shared__ float zlds[NN];
    __shared__ float r2[1024];

    if (tid < NN)
        zlds[tid] = BETA * z_out[b * NN + tid] + z[b * NN + tid];
    __syncthreads();

    const int n_loc = tid & 63;
    const int n     = nb + n_loc;
    const int jg    = tid >> 6;
    float d2 = 0.f;
#pragma unroll 4
    for (int j = jg; j < NN - 1; j += 16)
        d2 += zlds[j + (j >= n)] * w[(size_t)(N_IN + j) * NN + n];
    r2[tid] = d2;
    __syncthreads();

    if (tid < 64) {
        float d1 = 0.f;
#pragma unroll
        for (int kr = 0; kr < 4; ++kr)
            d1 += ws[((size_t)kr * BATCH + b) * NN + n];
        float d2s = 0.f;
#pragma unroll
        for (int g = 0; g < 16; ++g) d2s += r2[g * 64 + n_loc];
        const float vv    = v[b * NN + n];
        const float zz    = z[b * NN + n];
        const float v_new = ALPHA * vv + d1 + d2s - V_TH * zz;
        out[b * NN + n]                  = v_new;
        out[BATCH * NN + b * NN + n]     = (v_new - V_TH > 0.f) ? 1.f : 0.f;
        out[2 * BATCH * NN + b * NN + n] = zlds[n];
    }
}

extern "C" void kernel_launch(void* const* d_in, const int* in_sizes, int n_in,
                              void* d_out, int out_size, void* d_ws, size_t ws_size,
                              hipStream_t stream) {
    (void)in_sizes; (void)n_in; (void)out_size;
    const float* x     = (const float*)d_in[0];
    const float* v     = (const float*)d_in[1];
    const float* z     = (const float*)d_in[2];
    const float* z_out = (const float*)d_in[3];
    const float* w     = (const float*)d_in[4];
    float* out = (float*)d_out;
    float* wsf = (float*)d_ws;

    const size_t need32 = (size_t)32 * BATCH * NN * sizeof(float);   // 4 MB
    if (ws_size >= need32) {
        dim3 g1(32, BATCH / G);          // 512 blocks
        k1_stream<<<g1, 1024, 0, stream>>>(x, w, z, z_out, (float4*)wsf);
        k3_epi<<<BATCH * NN / 128, 128, 0, stream>>>(v, z, z_out, wsf, out);
    } else {
        dim3 g1(8, BATCH / G, 4);        // R10 fallback
        k1_fallback<<<g1, 1024, 0, stream>>>(x, w, (float4*)wsf);
        dim3 g2(8, BATCH);
        k2_finish<<<g2, 1024, 0, stream>>>(v, z, z_out, w, wsf, out);
    }
}